// Round 1
// baseline (746.697 us; speedup 1.0000x reference)
//
#include <hip/hip_runtime.h>
#include <cstdint>

// ---------------------------------------------------------------------------
// PureCorrelation: out = relu(mask(Q @ (K W1^T + b1)^T)) @ (V W2^T + b2)
// B=4, S=4096, E=512, fp32 in/out. Strategy: cast to bf16, run 4 GEMMs with
// one m97-style gemm_bt kernel (128x128 tile, BK=32, global_load_lds w=16,
// 16x16x32 bf16 MFMA). V-projection computed transposed (W2 @ V^T) so the AV
// GEMM also sees a B^T operand.
// ---------------------------------------------------------------------------

typedef __bf16 bf16x8 __attribute__((ext_vector_type(8)));
typedef float f32x4 __attribute__((ext_vector_type(4)));

__device__ __forceinline__ unsigned short f2bf(float f) {
  // round-to-nearest-even fp32 -> bf16
  unsigned int u = __float_as_uint(f);
  u += 0x7fffu + ((u >> 16) & 1u);
  return (unsigned short)(u >> 16);
}

// async global->LDS, 16B per lane. LDS dest is wave-uniform base + lane*16.
__device__ __forceinline__ void async_load16(const void* g, void* l) {
  __builtin_amdgcn_global_load_lds(
      (const __attribute__((address_space(1))) unsigned int*)(uintptr_t)g,
      (__attribute__((address_space(3))) unsigned int*)(unsigned int)(uintptr_t)l,
      16, 0, 0);
}

// fp32 -> bf16 cast, 4 elements/thread
__global__ void cvt_f32_bf16(const float* __restrict__ in,
                             unsigned short* __restrict__ out, int n4) {
  int i = blockIdx.x * blockDim.x + threadIdx.x;
  if (i < n4) {
    float4 f = ((const float4*)in)[i];
    ushort4 o;
    o.x = f2bf(f.x); o.y = f2bf(f.y); o.z = f2bf(f.z); o.w = f2bf(f.w);
    ((ushort4*)out)[i] = o;
  }
}

// C = A[M,K] @ B[N,K]^T (+ epilogue). Row-major, lda=K, ldb=K, ldc=N.
// EPI: 0 = +bias[n], store bf16        (K projection)
//      1 = +bias[m], store bf16        (V projection, transposed output)
//      2 = mask+relu, store bf16       (alpha; mask col 0 forced true)
//      3 = plain, store fp32           (final output)
template <int EPI>
__global__ void __launch_bounds__(256)
gemm_bt(const unsigned short* __restrict__ A, const unsigned short* __restrict__ B,
        void* __restrict__ Cout, const float* __restrict__ bias,
        const int* __restrict__ mask,
        int M, int N, int K,
        long long strA, long long strB, long long strC, long long strM) {
  __shared__ unsigned short sA[128 * 32];
  __shared__ unsigned short sB[128 * 32];

  const int tid  = threadIdx.x;
  const int lane = tid & 63;
  const int wave = tid >> 6;
  const int bz   = blockIdx.z;
  const int tn0  = blockIdx.x * 128;
  const int tm0  = blockIdx.y * 128;

  const unsigned short* Ab = A + (size_t)bz * strA;
  const unsigned short* Bb = B + (size_t)bz * strB;

  const int ldrow = lane >> 2;        // row within a 16-row wave-load
  const int lcol  = (lane & 3) * 8;   // k-element offset within BK=32

  const int wm = (wave >> 1) * 64;    // wave tile origin in 128x128 block
  const int wn = (wave & 1) * 64;
  const int lr = lane & 15;           // frag row (m or n)
  const int lq = lane >> 4;           // quad: k offset = lq*8, C row = lq*4+r

  f32x4 acc[4][4] = {};

  for (int k0 = 0; k0 < K; k0 += 32) {
    // --- stage A and B tiles (128x32 bf16 each) via global_load_lds ---
#pragma unroll
    for (int l = 0; l < 2; ++l) {
      const int row = wave * 32 + l * 16;  // wave-uniform LDS base row
      async_load16(Ab + (size_t)(tm0 + row + ldrow) * K + (k0 + lcol), &sA[row * 32]);
      async_load16(Bb + (size_t)(tn0 + row + ldrow) * K + (k0 + lcol), &sB[row * 32]);
    }
    __syncthreads();

    bf16x8 af[4], bfr[4];
#pragma unroll
    for (int t = 0; t < 4; ++t) {
      af[t]  = *(const bf16x8*)&sA[(wm + t * 16 + lr) * 32 + lq * 8];
      bfr[t] = *(const bf16x8*)&sB[(wn + t * 16 + lr) * 32 + lq * 8];
    }
#pragma unroll
    for (int mt = 0; mt < 4; ++mt)
#pragma unroll
      for (int nt = 0; nt < 4; ++nt)
        acc[mt][nt] = __builtin_amdgcn_mfma_f32_16x16x32_bf16(af[mt], bfr[nt],
                                                              acc[mt][nt], 0, 0, 0);
    __syncthreads();
  }

  // --- epilogue: C/D layout col = lane&15, row = (lane>>4)*4 + reg ---
#pragma unroll
  for (int mt = 0; mt < 4; ++mt) {
#pragma unroll
    for (int nt = 0; nt < 4; ++nt) {
#pragma unroll
      for (int r = 0; r < 4; ++r) {
        const int m = tm0 + wm + mt * 16 + lq * 4 + r;
        const int n = tn0 + wn + nt * 16 + lr;
        float v = acc[mt][nt][r];
        if constexpr (EPI == 0) {
          v += bias[n];
          ((unsigned short*)Cout)[(size_t)bz * strC + (size_t)m * N + n] = f2bf(v);
        } else if constexpr (EPI == 1) {
          v += bias[m];
          ((unsigned short*)Cout)[(size_t)bz * strC + (size_t)m * N + n] = f2bf(v);
        } else if constexpr (EPI == 2) {
          const int ok = (n == 0) ? 1 : mask[(size_t)bz * strM + (size_t)m * N + n];
          v = (ok != 0) ? fmaxf(v, 0.f) : 0.f;
          ((unsigned short*)Cout)[(size_t)bz * strC + (size_t)m * N + n] = f2bf(v);
        } else {
          ((float*)Cout)[(size_t)bz * strC + (size_t)m * N + n] = v;
        }
      }
    }
  }
}

extern "C" void kernel_launch(void* const* d_in, const int* in_sizes, int n_in,
                              void* d_out, int out_size, void* d_ws, size_t ws_size,
                              hipStream_t stream) {
  const float* query = (const float*)d_in[0];
  const float* key   = (const float*)d_in[1];
  const float* value = (const float*)d_in[2];
  const int*   mask  = (const int*)d_in[3];
  const float* W1    = (const float*)d_in[4];
  const float* b1    = (const float*)d_in[5];
  const float* W2    = (const float*)d_in[6];
  const float* b2    = (const float*)d_in[7];
  float* out = (float*)d_out;

  constexpr int B = 4, S = 4096, E = 512;
  constexpr long long BSE = (long long)B * S * E;   // 8388608
  constexpr long long SE  = (long long)S * E;       // 2097152
  constexpr long long SS  = (long long)S * S;       // 16777216
  constexpr long long EE  = (long long)E * E;       // 262144

  // workspace carve-up (bytes): total ~209 MB
  char* ws = (char*)d_ws;
  unsigned short* Qb   = (unsigned short*)ws;  ws += BSE * 2;
  unsigned short* Kb   = (unsigned short*)ws;  ws += BSE * 2;
  unsigned short* Vb   = (unsigned short*)ws;  ws += BSE * 2;
  unsigned short* W1b  = (unsigned short*)ws;  ws += EE * 2;
  unsigned short* W2b  = (unsigned short*)ws;  ws += EE * 2;
  unsigned short* Kp   = (unsigned short*)ws;  ws += BSE * 2;  // [B*S, E]
  unsigned short* Vpt  = (unsigned short*)ws;  ws += BSE * 2;  // [B][E][S]
  unsigned short* alph = (unsigned short*)ws;  ws += SS * B * 2; // [B][S][S]

  // fp32 -> bf16 casts
  cvt_f32_bf16<<<dim3(BSE / 1024), 256, 0, stream>>>(query, Qb, (int)(BSE / 4));
  cvt_f32_bf16<<<dim3(BSE / 1024), 256, 0, stream>>>(key,   Kb, (int)(BSE / 4));
  cvt_f32_bf16<<<dim3(BSE / 1024), 256, 0, stream>>>(value, Vb, (int)(BSE / 4));
  cvt_f32_bf16<<<dim3(EE / 1024),  256, 0, stream>>>(W1, W1b, (int)(EE / 4));
  cvt_f32_bf16<<<dim3(EE / 1024),  256, 0, stream>>>(W2, W2b, (int)(EE / 4));

  // Kp[b*S+s, f] = sum_e Kb[s,e] W1[f,e] + b1[f]   (M=B*S, N=E, K=E)
  gemm_bt<0><<<dim3(E / 128, (B * S) / 128, 1), 256, 0, stream>>>(
      Kb, W1b, Kp, b1, nullptr, B * S, E, E, 0, 0, 0, 0);

  // Vpt[b][f][s] = sum_e W2[f,e] Vb[b,s,e] + b2[f]  (M=E, N=S, K=E, per batch)
  gemm_bt<1><<<dim3(S / 128, E / 128, B), 256, 0, stream>>>(
      W2b, Vb, Vpt, b2, nullptr, E, S, E, 0, SE, SE, 0);

  // alpha[b][q][k] = relu(mask(sum_e Qb[b,q,e] Kp[b,k,e]))  (M=N=S, K=E)
  gemm_bt<2><<<dim3(S / 128, S / 128, B), 256, 0, stream>>>(
      Qb, Kp, alph, nullptr, mask, S, S, E, SE, SE, SS, SS);

  // out[b][q][f] = sum_k alpha[b,q,k] Vpt[b,f,k]   (M=S, N=E, K=S)
  gemm_bt<3><<<dim3(E / 128, S / 128, B), 256, 0, stream>>>(
      alph, Vpt, out, nullptr, nullptr, S, E, S, SS, SE, SE, 0);
}